// Round 4
// baseline (280.191 us; speedup 1.0000x reference)
//
#include <hip/hip_runtime.h>

// ---------------------------------------------------------------------------
// out[n] = x_n^T A x_n / (x_n^T x_n),  A = Re(U^H Z U), U = full circuit unitary
// Kernel 1: simulate circuit on 128 basis columns -> U (complex fp32) in ws
// Kernel 2: A_ij -> bf16, with k-columns PERMUTED by pi (see below)
// Kernel 3: bf16 MFMA GEMM y = A x fused with dot/norm epilogue
//
// R3 -> R4:
//  * pi-permuted k-layout: B-frag element (kt,g,j2,j10) <-> x[n][32kt+16j2+4g+j10],
//    which is exactly the C/D-layout element (t=2kt+j2, r=j10) the epilogue
//    needs -> epilogue re-read eliminated; 8 loads/lane/iter instead of 16.
//  * amdgpu_waves_per_eu(4,4): pin 128-VGPR budget (R2: min-only bound let
//    the allocator drop to 64 regs and spill 66 MB to scratch).
//  * 1-deep register prefetch of the next tile's 8-load batch.
//  * build_A rewritten: 128 blocks x 128 threads (was 1 wave/CU, ~10 us).
// ---------------------------------------------------------------------------

#define N_QUBITS 7
#define DIM 128
#define N_LAYERS 4
#define BATCH 262144
#define GRID 1024
#define NT (BATCH / 64)          // 4096 tiles; GRID*4 == NT exactly

typedef short short8 __attribute__((ext_vector_type(8)));
typedef float f32x4 __attribute__((ext_vector_type(4)));

__device__ __forceinline__ unsigned short f2bf(float f) {
  unsigned u = __builtin_bit_cast(unsigned, f);
  u += 0x7fffu + ((u >> 16) & 1u);   // RNE
  return (unsigned short)(u >> 16);
}

// [bf16(x) | bf16(y)<<16], round-half-up: 1 add per value + 1 v_perm per pair
__device__ __forceinline__ unsigned pk2(float x, float y) {
  unsigned ux = __builtin_bit_cast(unsigned, x) + 0x8000u;
  unsigned uy = __builtin_bit_cast(unsigned, y) + 0x8000u;
  return __builtin_amdgcn_perm(uy, ux, 0x07060302u);
}

__device__ __forceinline__ short8 pack_bf16(float4 lo, float4 hi) {
  uint4 d;
  d.x = pk2(lo.x, lo.y);
  d.y = pk2(lo.z, lo.w);
  d.z = pk2(hi.x, hi.y);
  d.w = pk2(hi.z, hi.w);
  return __builtin_bit_cast(short8, d);
}

// ---------------------------------------------------------------------------
// Kernel 1: one block (64 threads) per column c. State (128 complex) in LDS.
// ---------------------------------------------------------------------------
__global__ void sim_columns(const float* __restrict__ W,
                            float* __restrict__ Ur, float* __restrict__ Ui) {
  __shared__ float sr[DIM], si[DIM];
  const int c = blockIdx.x;
  const int t = threadIdx.x;  // 0..63

  sr[t] = (t == c) ? 1.f : 0.f;        si[t] = 0.f;
  sr[t + 64] = (t + 64 == c) ? 1.f : 0.f;  si[t + 64] = 0.f;
  __syncthreads();

  for (int l = 0; l < N_LAYERS; ++l) {
    for (int w = 0; w < N_QUBITS; ++w) {
      const float phi = W[(l * 7 + w) * 3 + 0];
      const float th  = W[(l * 7 + w) * 3 + 1];
      const float om  = W[(l * 7 + w) * 3 + 2];
      const float ch = __cosf(0.5f * th), sh = __sinf(0.5f * th);
      const float ap = 0.5f * (phi + om), am = 0.5f * (phi - om);
      const float cap = __cosf(ap), sap = __sinf(ap);
      const float cam = __cosf(am), sam = __sinf(am);
      const float ar =  cap * ch, ai = -sap * ch;
      const float br = -cam * sh, bi = -sam * sh;
      const float cr =  cam * sh, ci = -sam * sh;
      const float dr =  cap * ch, di =  sap * ch;

      const int m = 1 << (6 - w);
      const int i0 = ((t & ~(m - 1)) << 1) | (t & (m - 1));
      const int i1 = i0 | m;
      const float x0r = sr[i0], x0i = si[i0];
      const float x1r = sr[i1], x1i = si[i1];
      __syncthreads();
      sr[i0] = ar * x0r - ai * x0i + br * x1r - bi * x1i;
      si[i0] = ar * x0i + ai * x0r + br * x1i + bi * x1r;
      sr[i1] = cr * x0r - ci * x0i + dr * x1r - di * x1i;
      si[i1] = cr * x0i + ci * x0r + dr * x1i + di * x1r;
      __syncthreads();
    }
    const int r = (l % (N_QUBITS - 1)) + 1;  // ranges [1,2,3,4]
    for (int w = 0; w < N_QUBITS; ++w) {
      const int ctrl = w, tgt = (w + r) % N_QUBITS;
      const int cmask = 1 << (6 - ctrl), tmask = 1 << (6 - tgt);
      const int i0 = ((t & ~(tmask - 1)) << 1) | (t & (tmask - 1));
      const int i1 = i0 | tmask;
      const float a0r = sr[i0], a0i = si[i0];
      const float a1r = sr[i1], a1i = si[i1];
      __syncthreads();
      if (i0 & cmask) {
        sr[i0] = a1r; si[i0] = a1i;
        sr[i1] = a0r; si[i1] = a0i;
      }
      __syncthreads();
    }
  }
  Ur[(size_t)t * DIM + c]        = sr[t];
  Ui[(size_t)t * DIM + c]        = si[t];
  Ur[(size_t)(t + 64) * DIM + c] = sr[t + 64];
  Ui[(size_t)(t + 64) * DIM + c] = si[t + 64];
}

// ---------------------------------------------------------------------------
// Kernel 2: Ab[i][k'] = f2bf( sum_k z_k (Ur[k][i]Ur[k][p] + Ui[k][i]Ui[k][p]) )
// with p = pi(k'):  k' bits [6:5]=kt [4:3]=g [2]=j2 [1:0]=j10
//                   p  = kt<<5 | j2<<4 | g<<2 | j10
// 128 blocks (row i) x 128 threads (k'); Ur[k][i] broadcasts, Ur[k][p]
// coalesces within the 512B row; everything L2-hot.
// ---------------------------------------------------------------------------
__global__ void build_A(const float* __restrict__ Ur, const float* __restrict__ Ui,
                        unsigned short* __restrict__ Ab) {
  const int i = blockIdx.x;
  const int kp = threadIdx.x;
  const int p = (kp & 0x60) | ((kp & 0x04) << 2) | ((kp & 0x18) >> 1) | (kp & 0x03);
  float s = 0.f;
#pragma unroll 8
  for (int k = 0; k < DIM; ++k) {
    const float zk = (((k >> 6) ^ k) & 1) ? -1.f : 1.f;
    s += zk * (Ur[k * DIM + i] * Ur[k * DIM + p] + Ui[k * DIM + i] * Ui[k * DIM + p]);
  }
  Ab[i * DIM + kp] = f2bf(s);
}

// ---------------------------------------------------------------------------
// Kernel 3: A in LDS (32KB, XOR-swizzled chunks, 0 conflicts measured R2).
//   A-frag: lane holds Ab[m = 16t + n16][k' = 32kt + 8g + j]   (pi-permuted)
//   B-frag: lane loads x[n16-row][32kt + 4g + j10 + 16 j2] as 2 float4 per kt
//           -> after pi these are exactly B elements j = 4*j2 + j10
//   C/D:    acc[t][r] = y[16t + 4g + r][n16];  epilogue element x[n][16t+4g+r]
//           == held load value (kt = t>>1, half = t&1, elem = r). No re-read.
// 4 blocks/CU (waves_per_eu(4,4) -> 128 VGPR pinned), 1-deep prefetch.
// ---------------------------------------------------------------------------
__attribute__((amdgpu_waves_per_eu(4, 4)))
__global__ __launch_bounds__(256) void vqa_main(const float* __restrict__ X,
                                                const unsigned short* __restrict__ Ab,
                                                float* __restrict__ out) {
  __shared__ unsigned short As[DIM * DIM];  // 32 KB

  const int tid = threadIdx.x;
  const int lane = tid & 63;
  const int wave = tid >> 6;
  const int n16 = lane & 15;
  const int g = lane >> 4;

  // ---- fill A into LDS with chunk swizzle (one-time, L2-hot source) ----
#pragma unroll
  for (int i = 0; i < 8; ++i) {
    const int q = tid + 256 * i;          // 16B-chunk id, 0..2047
    const int m = q >> 4, c = q & 15;
    const short8 v = *reinterpret_cast<const short8*>(Ab + q * 8);
    *reinterpret_cast<short8*>(As + m * DIM + ((c ^ (m & 15)) << 3)) = v;
  }
  __syncthreads();

  const unsigned short* abase[4];
#pragma unroll
  for (int kt = 0; kt < 4; ++kt)
    abase[kt] = As + n16 * DIM + (((4 * kt + g) ^ n16) << 3);

  // element offset of this lane's first float4: row (blk*64+wave*16+n16), col 4g
  int offs = (blockIdx.x * 64 + wave * 16 + n16) * DIM + 4 * g;
  const int delta = GRID * 64 * DIM;      // grid advance, elements

  float4 lo[4], hi[4];
#pragma unroll
  for (int kt = 0; kt < 4; ++kt) {
    lo[kt] = *reinterpret_cast<const float4*>(X + offs + 32 * kt);
    hi[kt] = *reinterpret_cast<const float4*>(X + offs + 32 * kt + 16);
  }

#pragma unroll 1
  for (int it = 0; it < NT / GRID; ++it) {
    // prefetch next tile's batch before the MFMA section
    float4 nlo[4], nhi[4];
    if (it < NT / GRID - 1) {
      const int o2 = offs + delta;
#pragma unroll
      for (int kt = 0; kt < 4; ++kt) {
        nlo[kt] = *reinterpret_cast<const float4*>(X + o2 + 32 * kt);
        nhi[kt] = *reinterpret_cast<const float4*>(X + o2 + 32 * kt + 16);
      }
    }

    f32x4 acc[8];
#pragma unroll
    for (int t = 0; t < 8; ++t) acc[t] = (f32x4){0.f, 0.f, 0.f, 0.f};

#pragma unroll
    for (int kt = 0; kt < 4; ++kt) {
      const short8 bf = pack_bf16(lo[kt], hi[kt]);
#pragma unroll
      for (int t = 0; t < 8; ++t) {
        const short8 af = *reinterpret_cast<const short8*>(abase[kt] + t * 16 * DIM);
        acc[t] = __builtin_amdgcn_mfma_f32_16x16x32_bf16(af, bf, acc[t], 0, 0, 0);
      }
    }

    // epilogue straight from held fp32 values (pi-layout match)
    float dot = 0.f, nrm = 0.f;
#pragma unroll
    for (int kt = 0; kt < 4; ++kt) {
      const f32x4 ae = acc[2 * kt], ao = acc[2 * kt + 1];
      dot += lo[kt].x * ae[0] + lo[kt].y * ae[1] + lo[kt].z * ae[2] + lo[kt].w * ae[3];
      dot += hi[kt].x * ao[0] + hi[kt].y * ao[1] + hi[kt].z * ao[2] + hi[kt].w * ao[3];
      nrm += lo[kt].x * lo[kt].x + lo[kt].y * lo[kt].y + lo[kt].z * lo[kt].z + lo[kt].w * lo[kt].w;
      nrm += hi[kt].x * hi[kt].x + hi[kt].y * hi[kt].y + hi[kt].z * hi[kt].z + hi[kt].w * hi[kt].w;
    }
    dot += __shfl_xor(dot, 16, 64);
    dot += __shfl_xor(dot, 32, 64);
    nrm += __shfl_xor(nrm, 16, 64);
    nrm += __shfl_xor(nrm, 32, 64);
    if (lane < 16) {
      const int n = blockIdx.x * 64 + wave * 16 + n16 + it * (GRID * 64);
      out[n] = dot / nrm;
    }

    if (it < NT / GRID - 1) {
#pragma unroll
      for (int kt = 0; kt < 4; ++kt) { lo[kt] = nlo[kt]; hi[kt] = nhi[kt]; }
      offs += delta;
    }
  }
}

// ---------------------------------------------------------------------------
extern "C" void kernel_launch(void* const* d_in, const int* in_sizes, int n_in,
                              void* d_out, int out_size, void* d_ws, size_t ws_size,
                              hipStream_t stream) {
  const float* X = (const float*)d_in[0];   // (262144, 128) fp32
  const float* W = (const float*)d_in[1];   // (4, 7, 3) fp32
  float* out = (float*)d_out;               // (262144,) fp32

  float* Ur = (float*)d_ws;
  float* Ui = Ur + DIM * DIM;
  unsigned short* Ab = (unsigned short*)(Ui + DIM * DIM);

  sim_columns<<<DIM, 64, 0, stream>>>(W, Ur, Ui);
  build_A<<<DIM, DIM, 0, stream>>>(Ur, Ui, Ab);
  vqa_main<<<GRID, 256, 0, stream>>>(X, Ab, out);
}

// Round 6
// 205.305 us; speedup vs baseline: 1.3648x; 1.3648x over previous
//
#include <hip/hip_runtime.h>

// ---------------------------------------------------------------------------
// out[n] = x_n^T A x_n / (x_n^T x_n),  A = Re(U^H Z U), U = full circuit unitary
// Kernel 1: simulate circuit on 128 basis columns -> U (complex fp32) in ws
// Kernel 2: A_ij = sum_k z_k (Ur_ki Ur_kj + Ui_ki Ui_kj) -> bf16 A in ws
// Kernel 3: bf16 MFMA GEMM y = A x fused with dot/norm epilogue
//
// R5 -> R6: R5's single-buffer X staging raced (tripwire nondeterminism):
// next-tile DMA wrote the LDS region being read, relying on barrier ordering
// the compiler may not honor for global_load_lds's LDS side-effect. Now X is
// DOUBLE-buffered: reads from buf[cur], DMA into buf[cur^1] -- disjoint, so
// no reordering can break it; one barrier/iter, and its vmcnt drain waits on
// a DMA issued a full iteration earlier (prefetch distance >= HBM latency).
// Block 128 thr / 2 waves, 32-row tiles, LDS 32+2x16=64KB -> 2 blocks/CU.
// ---------------------------------------------------------------------------

#define N_QUBITS 7
#define DIM 128
#define N_LAYERS 4
#define BATCH 262144
#define GRID 512
#define ROWS 32                          // rows per X tile
#define ITERS (BATCH / (GRID * ROWS))    // 16

typedef short short8 __attribute__((ext_vector_type(8)));
typedef float f32x4 __attribute__((ext_vector_type(4)));
typedef unsigned int u32;
typedef __attribute__((address_space(1))) const u32 g_u32;
typedef __attribute__((address_space(3))) u32 l_u32;

__device__ __forceinline__ unsigned short f2bf(float f) {
  unsigned u = __builtin_bit_cast(unsigned, f);
  u += 0x7fffu + ((u >> 16) & 1u);   // RNE
  return (unsigned short)(u >> 16);
}

// [bf16(x) | bf16(y)<<16]: round-half-up add + v_perm byte select
__device__ __forceinline__ unsigned pk2(float x, float y) {
  unsigned ux = __builtin_bit_cast(unsigned, x) + 0x8000u;
  unsigned uy = __builtin_bit_cast(unsigned, y) + 0x8000u;
  return __builtin_amdgcn_perm(uy, ux, 0x07060302u);
}

__device__ __forceinline__ short8 pack_bf16(float4 lo, float4 hi) {
  uint4 d;
  d.x = pk2(lo.x, lo.y);
  d.y = pk2(lo.z, lo.w);
  d.z = pk2(hi.x, hi.y);
  d.w = pk2(hi.z, hi.w);
  return __builtin_bit_cast(short8, d);
}

// ---------------------------------------------------------------------------
// Kernel 1: one block (64 threads) per column c. State (128 complex) in LDS.
// Qubit w <-> bit (6-w) of the flattened index.
// ---------------------------------------------------------------------------
__global__ void sim_columns(const float* __restrict__ W,
                            float* __restrict__ Ur, float* __restrict__ Ui) {
  __shared__ float sr[DIM], si[DIM];
  const int c = blockIdx.x;
  const int t = threadIdx.x;  // 0..63

  sr[t] = (t == c) ? 1.f : 0.f;        si[t] = 0.f;
  sr[t + 64] = (t + 64 == c) ? 1.f : 0.f;  si[t + 64] = 0.f;
  __syncthreads();

  for (int l = 0; l < N_LAYERS; ++l) {
    for (int w = 0; w < N_QUBITS; ++w) {
      const float phi = W[(l * 7 + w) * 3 + 0];
      const float th  = W[(l * 7 + w) * 3 + 1];
      const float om  = W[(l * 7 + w) * 3 + 2];
      const float ch = __cosf(0.5f * th), sh = __sinf(0.5f * th);
      const float ap = 0.5f * (phi + om), am = 0.5f * (phi - om);
      const float cap = __cosf(ap), sap = __sinf(ap);
      const float cam = __cosf(am), sam = __sinf(am);
      const float ar =  cap * ch, ai = -sap * ch;
      const float br = -cam * sh, bi = -sam * sh;
      const float cr =  cam * sh, ci = -sam * sh;
      const float dr =  cap * ch, di =  sap * ch;

      const int m = 1 << (6 - w);
      const int i0 = ((t & ~(m - 1)) << 1) | (t & (m - 1));
      const int i1 = i0 | m;
      const float x0r = sr[i0], x0i = si[i0];
      const float x1r = sr[i1], x1i = si[i1];
      __syncthreads();
      sr[i0] = ar * x0r - ai * x0i + br * x1r - bi * x1i;
      si[i0] = ar * x0i + ai * x0r + br * x1i + bi * x1r;
      sr[i1] = cr * x0r - ci * x0i + dr * x1r - di * x1i;
      si[i1] = cr * x0i + ci * x0r + dr * x1i + di * x1r;
      __syncthreads();
    }
    const int r = (l % (N_QUBITS - 1)) + 1;  // ranges [1,2,3,4]
    for (int w = 0; w < N_QUBITS; ++w) {
      const int ctrl = w, tgt = (w + r) % N_QUBITS;
      const int cmask = 1 << (6 - ctrl), tmask = 1 << (6 - tgt);
      const int i0 = ((t & ~(tmask - 1)) << 1) | (t & (tmask - 1));
      const int i1 = i0 | tmask;
      const float a0r = sr[i0], a0i = si[i0];
      const float a1r = sr[i1], a1i = si[i1];
      __syncthreads();
      if (i0 & cmask) {
        sr[i0] = a1r; si[i0] = a1i;
        sr[i1] = a0r; si[i1] = a0i;
      }
      __syncthreads();
    }
  }
  Ur[(size_t)t * DIM + c]        = sr[t];
  Ui[(size_t)t * DIM + c]        = si[t];
  Ur[(size_t)(t + 64) * DIM + c] = sr[t + 64];
  Ui[(size_t)(t + 64) * DIM + c] = si[t + 64];
}

// ---------------------------------------------------------------------------
// Kernel 2: A_ij, identity k-layout. 128 blocks (row i) x 128 threads (j).
// Ur[k][i] broadcasts; Ur[k][j] coalesces; all L2-hot.
// ---------------------------------------------------------------------------
__global__ void build_A(const float* __restrict__ Ur, const float* __restrict__ Ui,
                        unsigned short* __restrict__ Ab) {
  const int i = blockIdx.x;
  const int j = threadIdx.x;
  float s = 0.f;
#pragma unroll 8
  for (int k = 0; k < DIM; ++k) {
    const float zk = (((k >> 6) ^ k) & 1) ? -1.f : 1.f;
    s += zk * (Ur[k * DIM + i] * Ur[k * DIM + j] + Ui[k * DIM + i] * Ui[k * DIM + j]);
  }
  Ab[i * DIM + j] = f2bf(s);
}

// ---------------------------------------------------------------------------
// DMA one 32-row X tile (16 KB) into the given Xs buffer. LDS slot
// s = tid + 128j holds global chunk (row = s>>5, c = (s&31) ^ (row&7)) --
// source-side swizzle because the DMA's LDS dest is wave-uniform base +
// lane*16 (m104) and can't scatter. Per wave the 64 lane dests are
// contiguous 16B slots in lane order, as the hardware requires.
// ---------------------------------------------------------------------------
__device__ __forceinline__ void stage_tile(const float* __restrict__ X, float* XsBuf,
                                           int tile, int tid) {
#pragma unroll
  for (int j = 0; j < 8; ++j) {
    const int s = tid + 128 * j;              // LDS 16B-slot id, 0..1023
    const int row = s >> 5;
    const int c = (s & 31) ^ (row & 7);       // swizzled source chunk
    const float* gp = X + (size_t)tile * (ROWS * DIM) + row * DIM + c * 4;
    __builtin_amdgcn_global_load_lds((g_u32*)gp, (l_u32*)(XsBuf + s * 4), 16, 0, 0);
  }
}

// ---------------------------------------------------------------------------
// Kernel 3. Block = 2 waves; wave w owns tile rows 16w..16w+15.
//   A-frag: lane holds Ab[m = 16t + n16][k = 32kt + 8g + j]   (LDS, swizzled)
//   B-frag: row R = 16w + n16, chunks (8kt+2g)^rx, (8kt+2g+1)^rx (2x b128)
//   C/D:    acc[t][r] = y[16t + 4g + r][n16]; epilogue xe chunk (4t+g)^rx,
//           read AFTER the MFMAs (cur buffer stays intact -- dbuf).
// Quarter-wave read phases (fixed g, R over 16 rows): (c0 ^ (R&7)) covers
// every 4-bank group exactly twice = 2-way = free (m136).
// One barrier per iteration; its vmcnt drain targets the DMA issued in the
// PREVIOUS iteration body (prefetch distance ~ a full iteration of compute).
// ---------------------------------------------------------------------------
__global__ __launch_bounds__(128, 2) void vqa_main(const float* __restrict__ X,
                                                   const unsigned short* __restrict__ Ab,
                                                   float* __restrict__ out) {
  __shared__ unsigned short As[DIM * DIM];   // 32 KB
  __shared__ float Xs[2 * ROWS * DIM];       // 2 x 16 KB

  const int tid = threadIdx.x;   // 0..127
  const int lane = tid & 63;
  const int wave = tid >> 6;     // 0..1
  const int n16 = lane & 15;
  const int g = lane >> 4;

  // start DMA of tile 0 into buf 0; flies under the A-fill
  stage_tile(X, Xs, blockIdx.x, tid);

  // fill A into LDS with chunk swizzle (source L2-hot); 16 chunks/thread
#pragma unroll
  for (int i = 0; i < 16; ++i) {
    const int q = tid + 128 * i;          // 16B-chunk id, 0..2047
    const int m = q >> 4, c = q & 15;
    const short8 v = *reinterpret_cast<const short8*>(Ab + q * 8);
    *reinterpret_cast<short8*>(As + m * DIM + ((c ^ (m & 15)) << 3)) = v;
  }

  const unsigned short* abase[4];
#pragma unroll
  for (int kt = 0; kt < 4; ++kt)
    abase[kt] = As + n16 * DIM + (((4 * kt + g) ^ n16) << 3);

  const int R = 16 * wave + n16;   // this lane's row within the tile (0..31)
  const int rx = R & 7;            // row swizzle key

#pragma unroll 1
  for (int it = 0; it < ITERS; ++it) {
    const int cur = it & 1;
    const int rb = cur * (ROWS * 32) + R * 32;   // row's first slot in cur buf

    // drain: DMA(cur) issued last iteration (+ A-fill on it==0), then barrier
    asm volatile("s_waitcnt vmcnt(0)" ::: "memory");
    __syncthreads();

    // B-fragments from LDS
    short8 bfrag[4];
#pragma unroll
    for (int kt = 0; kt < 4; ++kt) {
      const int c0 = 8 * kt + 2 * g;
      const float4 lo = *reinterpret_cast<const float4*>(Xs + (rb + (c0 ^ rx)) * 4);
      const float4 hi = *reinterpret_cast<const float4*>(Xs + (rb + ((c0 + 1) ^ rx)) * 4);
      bfrag[kt] = pack_bf16(lo, hi);
    }

    // issue next tile's DMA into the OTHER buffer (no aliasing possible)
    if (it + 1 < ITERS)
      stage_tile(X, Xs + (cur ^ 1) * (ROWS * DIM), blockIdx.x + (it + 1) * GRID, tid);

    f32x4 acc[8];
#pragma unroll
    for (int t = 0; t < 8; ++t) acc[t] = (f32x4){0.f, 0.f, 0.f, 0.f};
#pragma unroll
    for (int kt = 0; kt < 4; ++kt) {
#pragma unroll
      for (int t = 0; t < 8; ++t) {
        const short8 af = *reinterpret_cast<const short8*>(abase[kt] + t * 16 * DIM);
        acc[t] = __builtin_amdgcn_mfma_f32_16x16x32_bf16(af, bfrag[kt], acc[t], 0, 0, 0);
      }
    }

    // epilogue: x re-read from the (still intact) cur buffer after MFMAs
    float dot = 0.f, nrm = 0.f;
#pragma unroll
    for (int t = 0; t < 8; ++t) {
      const float4 xe = *reinterpret_cast<const float4*>(Xs + (rb + ((4 * t + g) ^ rx)) * 4);
      dot += xe.x * acc[t][0] + xe.y * acc[t][1] + xe.z * acc[t][2] + xe.w * acc[t][3];
      nrm += xe.x * xe.x + xe.y * xe.y + xe.z * xe.z + xe.w * xe.w;
    }
    dot += __shfl_xor(dot, 16, 64);
    dot += __shfl_xor(dot, 32, 64);
    nrm += __shfl_xor(nrm, 16, 64);
    nrm += __shfl_xor(nrm, 32, 64);
    if (lane < 16) out[(blockIdx.x + it * GRID) * ROWS + R] = dot / nrm;
  }
}

// ---------------------------------------------------------------------------
extern "C" void kernel_launch(void* const* d_in, const int* in_sizes, int n_in,
                              void* d_out, int out_size, void* d_ws, size_t ws_size,
                              hipStream_t stream) {
  const float* X = (const float*)d_in[0];   // (262144, 128) fp32
  const float* W = (const float*)d_in[1];   // (4, 7, 3) fp32
  float* out = (float*)d_out;               // (262144,) fp32

  float* Ur = (float*)d_ws;
  float* Ui = Ur + DIM * DIM;
  unsigned short* Ab = (unsigned short*)(Ui + DIM * DIM);

  sim_columns<<<DIM, 64, 0, stream>>>(W, Ur, Ui);
  build_A<<<DIM, DIM, 0, stream>>>(Ur, Ui, Ab);
  vqa_main<<<GRID, 128, 0, stream>>>(X, Ab, out);
}